// Round 11
// baseline (316.103 us; speedup 1.0000x reference)
//
#include <hip/hip_runtime.h>
#include <stdint.h>

// ---------------------------------------------------------------------------
// CausalSelfAttention: x[4,2048,1024] -> qkv -> flash attn -> proj
// Round 14: flash counted-vmcnt double-buffer at EXACTLY 40 KiB LDS.
// R10's register-prefetch spilled to scratch (WRITE_SIZE 322 MB); R4's dbuf
// cost occupancy (49K LDS -> 3 blk/CU).  This version: lK/lVT double-buffered
// (32K) + lP shrunk to ONE tile @ stride 64 with XOR swizzle (8K) = 40960 B
// -> 4 blocks/CU kept.  Loop: issue kv+1's GL16s -> s_waitcnt vmcnt(4)
// (waits only on loads issued a FULL iteration ago ~ free) -> raw s_barrier
// (NOT __syncthreads, which re-drains vmcnt) -> compute -> barrier.
// lP swizzle col^=((row&7)<<3): writes ~2-way (free), pf b128 reads
// conflict-free.  PV restructured B-then-A (lP reused; vf re-read for A).
// GEMMs (R8 1-barrier dbuf), k_prep, k_tv unchanged from R9.
// ---------------------------------------------------------------------------

typedef __attribute__((ext_vector_type(8))) short short8;   // 8 bf16 (4 VGPRs)
typedef __attribute__((ext_vector_type(4))) float floatx4;  // MFMA C/D frag

#define AS1C(p) ((const __attribute__((address_space(1))) void*)(p))
#define AS3(p)  ((__attribute__((address_space(3))) void*)(p))
#define GL16(src, dst) __builtin_amdgcn_global_load_lds(AS1C(src), AS3(dst), 16, 0, 0)
#define BARRIER() do { asm volatile("" ::: "memory"); __builtin_amdgcn_s_barrier(); asm volatile("" ::: "memory"); } while (0)

__device__ __forceinline__ unsigned short f2bf(float f) {
  unsigned int u = __builtin_bit_cast(unsigned int, f);
  u = (u + 0x7fffu + ((u >> 16) & 1u)) >> 16;   // RNE
  return (unsigned short)u;
}
__device__ __forceinline__ unsigned short f2bf_trunc(float f) {
  return (unsigned short)(__builtin_bit_cast(unsigned int, f) >> 16);
}

// ---------------------------------------------------------------------------
// Fused prep: [0,8192) cvt x->bf16; [8192,11264) tw W_attn; [11264,12288) tw
// W_proj.
// ---------------------------------------------------------------------------
__global__ __launch_bounds__(256)
void k_prep(const float* __restrict__ x, unsigned short* __restrict__ xb,
            const float* __restrict__ Wa, unsigned short* __restrict__ WaT,
            const float* __restrict__ Wp, unsigned short* __restrict__ WpT) {
  __shared__ float t[32][33];
  int bid = blockIdx.x;
  int tid = threadIdx.x;
  if (bid < 8192) {
    int i = bid * 256 + tid;           // n4 = 2097152 = 8192*256 exactly
    float4 v = ((const float4*)x)[i];
    ushort4 o;
    o.x = f2bf(v.x); o.y = f2bf(v.y); o.z = f2bf(v.z); o.w = f2bf(v.w);
    ((ushort4*)xb)[i] = o;
    return;
  }
  const float* in; unsigned short* out; int K = 1024, N, n0, k0;
  if (bid < 11264) {                   // W_attn: 96x32 tiles of [1024][3072]
    int b2 = bid - 8192;
    in = Wa; out = WaT; N = 3072;
    n0 = (b2 % 96) * 32; k0 = (b2 / 96) * 32;
  } else {                             // W_proj: 32x32 tiles of [1024][1024]
    int b2 = bid - 11264;
    in = Wp; out = WpT; N = 1024;
    n0 = (b2 % 32) * 32; k0 = (b2 / 32) * 32;
  }
  int tx = tid & 31, ty = tid >> 5;
#pragma unroll
  for (int i = 0; i < 4; i++)
    t[ty + 8 * i][tx] = in[(size_t)(k0 + ty + 8 * i) * N + n0 + tx];
  __syncthreads();
#pragma unroll
  for (int i = 0; i < 4; i++)
    out[(size_t)(n0 + ty + 8 * i) * K + k0 + tx] = f2bf(t[tx][ty + 8 * i]);
}

// ---- transpose V slice of qkv (bf16) -> VT[bh][d][t], 64-wide tiles ----
__global__ __launch_bounds__(256)
void k_tv(const unsigned short* __restrict__ qkv, unsigned short* __restrict__ vt) {
  __shared__ unsigned short t[64][65];
  int t0 = blockIdx.x * 64;         // time tile
  int bh = blockIdx.y;              // 0..63
  int b = bh >> 4, h = bh & 15;
  int tx = threadIdx.x & 63, ty = threadIdx.x >> 6;   // 64 x 4
#pragma unroll
  for (int i = 0; i < 16; i++)
    t[ty + 4 * i][tx] = qkv[(size_t)(b * 2048 + t0 + ty + 4 * i) * 3072 + 2048 + h * 64 + tx];
  __syncthreads();
#pragma unroll
  for (int i = 0; i < 16; i++)
    vt[(size_t)(bh * 64 + ty + 4 * i) * 2048 + t0 + tx] = t[tx][ty + 4 * i];
}

// ---------------------------------------------------------------------------
// 256x(NF*64)-tile bf16 GEMM, C = A[M,K] @ Bt[N,K]^T + bias.
// A+B double-buffered; one barrier + one vmcnt per K-tile (R8 schedule).
// ---------------------------------------------------------------------------
template <int OUT_F32, int NF>
__global__ __launch_bounds__(512, 2)
void k_gemm8(const unsigned short* __restrict__ A,
             const unsigned short* __restrict__ Bt,
             const float* __restrict__ bias,
             void* __restrict__ Cout, int M, int N, int K) {
  __shared__ unsigned short lA[2][256 * 64];        // 64 KiB
  __shared__ unsigned short lB[2][NF * 64 * 64];    // 48 (NF=3) / 32 (NF=2) KiB
  int tid = threadIdx.x;
  int lane = tid & 63, wv = tid >> 6;               // 8 waves
  int lc = lane & 15, quad = lane >> 4;
  int sw = lc & 7;

  // T1: XCD-aware block swizzle (nwg % 8 == 0 for both launches)
  unsigned nbx = gridDim.x;
  unsigned nwg = nbx * gridDim.y;
  unsigned flat = blockIdx.y * nbx + blockIdx.x;
  unsigned cpx = nwg >> 3;
  unsigned tile = (flat & 7u) * cpx + (flat >> 3);
  int n0 = (int)(tile % nbx) * (NF * 64);
  int m0 = (int)(tile / nbx) * 256;

  int wm = (wv >> 2) * 128;         // 0,128
  int wn = (wv & 3) * (NF * 16);    // 4 N-waves

  floatx4 acc[8][NF];
#pragma unroll
  for (int i = 0; i < 8; i++)
#pragma unroll
    for (int j = 0; j < NF; j++) acc[i][j] = (floatx4){0.f, 0.f, 0.f, 0.f};

  // staging geometry: one gload issue = 512 thr x 16B = 8 KiB = 64 rows
  int srow = tid >> 3;                          // 0..63
  int scol = ((tid & 7) ^ (srow & 7)) * 8;      // inverse-swizzled source chunk
  const unsigned short* gA = A + (size_t)(m0 + srow) * K + scol;
  const unsigned short* gB = Bt + (size_t)(n0 + srow) * K + scol;

  int NT = K >> 6;

  // prologue: stage K-tile 0 into parity 0; wait; barrier.
#pragma unroll
  for (int i = 0; i < 4; i++)  GL16(gA + (size_t)(i * 64) * K, &lA[0][i * 4096 + wv * 512]);
#pragma unroll
  for (int i = 0; i < NF; i++) GL16(gB + (size_t)(i * 64) * K, &lB[0][i * 4096 + wv * 512]);
  asm volatile("s_waitcnt vmcnt(0)" ::: "memory");
  __builtin_amdgcn_s_barrier();
  asm volatile("" ::: "memory");

  for (int t = 0; t < NT; ++t) {
    const unsigned short* bufA = lA[t & 1];
    const unsigned short* bufB = lB[t & 1];
    bool st = (t + 1) < NT;

    // issue next tile's staging FIRST (full-tile latency cover).
    if (st) {
      unsigned short* nA = lA[(t + 1) & 1];
      unsigned short* nB = lB[(t + 1) & 1];
      int k1 = (t + 1) << 6;
#pragma unroll
      for (int i = 0; i < 4; i++)
        GL16(gA + (size_t)(i * 64) * K + k1, nA + i * 4096 + wv * 512);
#pragma unroll
      for (int i = 0; i < NF; i++)
        GL16(gB + (size_t)(i * 64) * K + k1, nB + i * 4096 + wv * 512);
    }

    // ---- compute tile t: one barrier-free region ----
    short8 af[4][2], bf[NF][2];
#pragma unroll
    for (int n = 0; n < NF; n++)
#pragma unroll
      for (int ks = 0; ks < 2; ks++)
        bf[n][ks] = *(const short8*)(bufB + (wn + n * 16 + lc) * 64 + (((ks * 4 + quad) ^ sw) * 8));
#pragma unroll
    for (int m = 0; m < 4; m++)
#pragma unroll
      for (int ks = 0; ks < 2; ks++)
        af[m][ks] = *(const short8*)(bufA + (wm + m * 16 + lc) * 64 + (((ks * 4 + quad) ^ sw) * 8));
    __builtin_amdgcn_s_setprio(1);
#pragma unroll
    for (int m = 0; m < 4; m++)
#pragma unroll
      for (int n = 0; n < NF; n++)
#pragma unroll
        for (int ks = 0; ks < 2; ks++)
          acc[m][n] = __builtin_amdgcn_mfma_f32_16x16x32_bf16(af[m][ks], bf[n][ks], acc[m][n], 0, 0, 0);
    __builtin_amdgcn_s_setprio(0);
#pragma unroll
    for (int m = 0; m < 4; m++)
#pragma unroll
      for (int ks = 0; ks < 2; ks++)
        af[m][ks] = *(const short8*)(bufA + (wm + (m + 4) * 16 + lc) * 64 + (((ks * 4 + quad) ^ sw) * 8));
    __builtin_amdgcn_s_setprio(1);
#pragma unroll
    for (int m = 0; m < 4; m++)
#pragma unroll
      for (int n = 0; n < NF; n++)
#pragma unroll
        for (int ks = 0; ks < 2; ks++)
          acc[m + 4][n] = __builtin_amdgcn_mfma_f32_16x16x32_bf16(af[m][ks], bf[n][ks], acc[m + 4][n], 0, 0, 0);
    __builtin_amdgcn_s_setprio(0);

    // ---- tile boundary: t+1 landed (issued a full tile ago) + barrier ----
    if (st) {
      asm volatile("s_waitcnt vmcnt(0)" ::: "memory");
      BARRIER();
    }
  }

  // ---- epilogue ----
  float bv[NF];
#pragma unroll
  for (int j = 0; j < NF; j++) bv[j] = bias[n0 + wn + j * 16 + lc];
#pragma unroll
  for (int i = 0; i < 8; i++) {
#pragma unroll
    for (int j = 0; j < NF; j++) {
#pragma unroll
      for (int r = 0; r < 4; r++) {
        size_t idx = (size_t)(m0 + wm + i * 16 + quad * 4 + r) * N + (n0 + wn + j * 16 + lc);
        float v = acc[i][j][r] + bv[j];
        if (OUT_F32) ((float*)Cout)[idx] = v;
        else         ((unsigned short*)Cout)[idx] = f2bf(v);
      }
    }
  }
}

// ---- flash attention: paired q-tiles, XCD-grouped, counted-vmcnt dbuf ----
__global__ __launch_bounds__(256, 4)
void k_flash(const unsigned short* __restrict__ qkv,
             const unsigned short* __restrict__ vt,
             unsigned short* __restrict__ y) {
  __shared__ unsigned short lK[2][64 * 64];    // 16 KiB
  __shared__ unsigned short lVT[2][64 * 64];   // 16 KiB
  __shared__ unsigned short lP[4][16 * 64];    // 8 KiB  -> 40960 B total
  int tid = threadIdx.x, lane = tid & 63, wv = tid >> 6;
  int lc = lane & 15, quad = lane >> 4;
  int sw = lc & 7;

  // XCD grouping: each XCD owns 8 bh values with ALL 16 q-pair blocks.
  int raw = blockIdx.y * 16 + blockIdx.x;      // 0..1023
  int bh  = (raw & 7) * 8 + ((raw >> 3) & 7);  // 0..63
  int j   = raw >> 6;                          // 0..15
  int b = bh >> 4, h = bh & 15;
  int qtA = j, qtB = 31 - j;
  int qrA = qtA * 64 + wv * 16;
  int qrB = qtB * 64 + wv * 16;

  short8 qfA[2], qfB[2];
  {
    const unsigned short* qp = qkv + (size_t)(b * 2048 + qrA + lc) * 3072 + h * 64 + quad * 8;
    qfA[0] = *(const short8*)qp;
    qfA[1] = *(const short8*)(qp + 32);
  }
  {
    const unsigned short* qp = qkv + (size_t)(b * 2048 + qrB + lc) * 3072 + h * 64 + quad * 8;
    qfB[0] = *(const short8*)qp;
    qfB[1] = *(const short8*)(qp + 32);
  }

  float rsA[4] = {0.f, 0.f, 0.f, 0.f}, rsB[4] = {0.f, 0.f, 0.f, 0.f};
  floatx4 oA[4], oB[4];
#pragma unroll
  for (int dt = 0; dt < 4; dt++) {
    oA[dt] = (floatx4){0.f, 0.f, 0.f, 0.f};
    oB[dt] = (floatx4){0.f, 0.f, 0.f, 0.f};
  }

  int srow = tid >> 3;
  int scol = ((tid & 7) ^ (srow & 7)) * 8;    // swizzled gather column
  const unsigned short* gK = qkv + (size_t)(b * 2048 + srow) * 3072 + 1024 + h * 64 + scol;
  const unsigned short* gV = vt + (size_t)(bh * 64 + srow) * 2048 + scol;

  const float SC2 = 0.18033688011f;   // (1/sqrt(64)) * log2(e)
  int nt = qtB + 1;                   // >= 17

  // prologue: stage KV tile 0 into buffer 0 (no wait here).
#pragma unroll
  for (int c = 0; c < 2; c++) {
    GL16(gK + (size_t)(32 * c) * 3072, &lK[0][(32 * c + 8 * wv) * 64]);
    GL16(gV + (size_t)(32 * c) * 2048, &lVT[0][(32 * c + 8 * wv) * 64]);
  }

  for (int kv = 0; kv < nt; kv++) {
    int cur = kv & 1;
    // issue kv+1's loads into the other buffer, then counted vmcnt(4):
    // waits only on kv's loads (issued a full iteration ago) -> ~free.
    if (kv + 1 < nt) {
      int kn0 = (kv + 1) * 64;
#pragma unroll
      for (int c = 0; c < 2; c++) {
        GL16(gK + (size_t)(kn0 + 32 * c) * 3072, &lK[cur ^ 1][(32 * c + 8 * wv) * 64]);
        GL16(gV + (size_t)(32 * c) * 2048 + kn0, &lVT[cur ^ 1][(32 * c + 8 * wv) * 64]);
      }
      asm volatile("s_waitcnt vmcnt(4)" ::: "memory");
    } else {
      asm volatile("s_waitcnt vmcnt(0)" ::: "memory");
    }
    BARRIER();   // tile kv visible to all waves (raw barrier: no vmcnt drain)

    const unsigned short* cK = lK[cur];
    const unsigned short* cVT = lVT[cur];
    int kv0 = kv * 64;
    bool withA = (kv <= qtA);

    // ---- S = Q K^T for both q-tiles, sharing K fragments ----
    floatx4 sB[4], sA[4];
    __builtin_amdgcn_s_setprio(1);
#pragma unroll
    for (int n = 0; n < 4; n++) {
      short8 kf0 = *(const short8*)(cK + (n * 16 + lc) * 64 + ((quad ^ sw) * 8));
      short8 kf1 = *(const short8*)(cK + (n * 16 + lc) * 64 + (((4 + quad) ^ sw) * 8));
      floatx4 t = (floatx4){0.f, 0.f, 0.f, 0.f};
      t = __builtin_amdgcn_mfma_f32_16x16x32_bf16(qfB[0], kf0, t, 0, 0, 0);
      t = __builtin_amdgcn_mfma_f32_16x16x32_bf16(qfB[1], kf1, t, 0, 0, 0);
      sB[n] = t;
      if (withA) {
        floatx4 u = (floatx4){0.f, 0.f, 0.f, 0.f};
        u = __builtin_amdgcn_mfma_f32_16x16x32_bf16(qfA[0], kf0, u, 0, 0, 0);
        u = __builtin_amdgcn_mfma_f32_16x16x32_bf16(qfA[1], kf1, u, 0, 0, 0);
        sA[n] = u;
      }
    }
    __builtin_amdgcn_s_setprio(0);

    // ---- B tile: softmax -> lP (swizzled), PV_B ----
    {
      bool diag = (kv == qtB);
#pragma unroll
      for (int n = 0; n < 4; n++)
#pragma unroll
        for (int r = 0; r < 4; r++) {
          float arg = sB[n][r] * SC2;
          if (diag && (kv0 + n * 16 + lc > qrB + quad * 4 + r)) arg = -__builtin_inff();
          float p = __builtin_amdgcn_exp2f(arg);
          rsB[r] += p;
          int row = quad * 4 + r;
          lP[wv][row * 64 + ((n * 16 + lc) ^ ((row & 7) << 3))] = f2bf_trunc(p);
        }
    }
    __builtin_amdgcn_s_setprio(1);
#pragma unroll
    for (int s2 = 0; s2 < 2; s2++) {
      short8 pfB = *(const short8*)(&lP[wv][lc * 64 + ((s2 * 32 + quad * 8) ^ ((lc & 7) << 3))]);
#pragma unroll
      for (int dt = 0; dt < 4; dt++) {
        short8 vf = *(const short8*)(cVT + (dt * 16 + lc) * 64 + (((s2 * 4 + quad) ^ sw) * 8));
        oB[dt] = __builtin_amdgcn_mfma_f32_16x16x32_bf16(pfB, vf, oB[dt], 0, 0, 0);
      }
    }
    __builtin_amdgcn_s_setprio(0);

    // ---- A tile: softmax -> lP (reuse, same-wave DS order), PV_A ----
    if (withA) {
      bool diag = (kv == qtA);
#pragma unroll
      for (int n = 0; n < 4; n++)
#pragma unroll
        for (int r = 0; r < 4; r++) {
          float arg = sA[n][r] * SC2;
          if (diag && (kv0 + n * 16 + lc > qrA + quad * 4 + r)) arg = -__builtin_inff();
          float p = __builtin_amdgcn_exp2f(arg);
          rsA[r] += p;
          int row = quad * 4 + r;
          lP[wv][row * 64 + ((n * 16 + lc) ^ ((row & 7) << 3))] = f2bf_trunc(p);
        }
      __builtin_amdgcn_s_setprio(1);
#pragma unroll
      for (int s2 = 0; s2 < 2; s2++) {
        short8 pfA = *(const short8*)(&lP[wv][lc * 64 + ((s2 * 32 + quad * 8) ^ ((lc & 7) << 3))]);
#pragma unroll
        for (int dt = 0; dt < 4; dt++) {
          short8 vf = *(const short8*)(cVT + (dt * 16 + lc) * 64 + (((s2 * 4 + quad) ^ sw) * 8));
          oA[dt] = __builtin_amdgcn_mfma_f32_16x16x32_bf16(pfA, vf, oA[dt], 0, 0, 0);
        }
      }
      __builtin_amdgcn_s_setprio(0);
    }

    BARRIER();   // all waves done reading buf[cur] -> next iter may overwrite
  }

  // ---- epilogue: one row-sum butterfly, normalize, store both tiles ----
#pragma unroll
  for (int off = 1; off < 16; off <<= 1)
#pragma unroll
    for (int r = 0; r < 4; r++) {
      rsA[r] += __shfl_xor(rsA[r], off);
      rsB[r] += __shfl_xor(rsB[r], off);
    }
#pragma unroll
  for (int r = 0; r < 4; r++) {
    float invA = 1.0f / rsA[r];
    float invB = 1.0f / rsB[r];
#pragma unroll
    for (int dt = 0; dt < 4; dt++) {
      size_t ia = (size_t)(b * 2048 + qrA + quad * 4 + r) * 1024 + h * 64 + dt * 16 + lc;
      size_t ib = (size_t)(b * 2048 + qrB + quad * 4 + r) * 1024 + h * 64 + dt * 16 + lc;
      y[ia] = f2bf(oA[dt][r] * invA);
      y[ib] = f2bf(oB[dt][r] * invB);
    }
  }
}

extern "C" void kernel_launch(void* const* d_in, const int* in_sizes, int n_in,
                              void* d_out, int out_size, void* d_ws, size_t ws_size,
                              hipStream_t stream) {
  const float* x      = (const float*)d_in[0];
  const float* W_attn = (const float*)d_in[1];
  const float* b_attn = (const float*)d_in[2];
  const float* W_proj = (const float*)d_in[3];
  const float* b_proj = (const float*)d_in[4];

  char* ws = (char*)d_ws;
  unsigned short* xb     = (unsigned short*)ws;                    // 16.8 MB (reused as y)
  unsigned short* wattnT = (unsigned short*)(ws + 16777216);       // 6.3 MB
  unsigned short* wprojT = (unsigned short*)(ws + 23068672);       // 2.1 MB
  unsigned short* qkv    = (unsigned short*)(ws + 25165824);       // 50.3 MB
  unsigned short* vt     = (unsigned short*)(ws + 75497472);       // 16.8 MB -> total 92.3 MB
  unsigned short* y      = xb;   // xb dead after QKV GEMM

  // fused prep: cvt (8192 blocks) + tw W_attn (3072) + tw W_proj (1024)
  k_prep<<<12288, 256, 0, stream>>>(x, xb, W_attn, wattnT, W_proj, wprojT);
  // QKV GEMM: 256x192 tiles, grid 16x32 = 512 blocks = 2 exact rounds
  k_gemm8<0, 3><<<dim3(16, 32), 512, 0, stream>>>(xb, wattnT, b_attn, qkv, 8192, 3072, 1024);
  // V transpose: 64-wide tiles, fully coalesced
  k_tv<<<dim3(32, 64), 256, 0, stream>>>(qkv, vt);
  k_flash<<<dim3(16, 64), 256, 0, stream>>>(qkv, vt, y);
  // proj GEMM: 256x128 tiles, grid 8x32 = 256 blocks = 1 exact round
  k_gemm8<1, 2><<<dim3(8, 32), 512, 0, stream>>>(y, wprojT, b_proj, d_out, 8192, 1024, 1024);
}

// Round 14
// 244.666 us; speedup vs baseline: 1.2920x; 1.2920x over previous
//
#include <hip/hip_runtime.h>
#include <stdint.h>

// ---------------------------------------------------------------------------
// CausalSelfAttention: x[4,2048,1024] -> qkv -> flash attn -> proj
// Round 17 (= round 15 resubmitted; R12 container failure + R13 acquisition
// timeout were both infra, no code change):
// flash split-wait schedule with ZERO new state (R4/R10/R11 all failed by
// adding LDS or register state; the R9 flash is the only stable operating
// point at 64 VGPR / 33.8 KB).  Single-buffered lK/lVT kept.
// Per iter: issue V(kv); vmcnt(2)+bar (K(kv) landed -- it was issued in the
// PREVIOUS iter after the mid-barrier, latency hidden under PV); QK^T +
// softmax (hides V latency); vmcnt(0)+bar (V landed); issue K(kv+1) (legal:
// all waves' lK reads retired before their mid-barrier); PV; end barrier.
// Both fetch latencies hidden; 3 barriers/iter; no extra LDS/VGPR.
// GEMMs (R8 1-barrier dbuf), k_prep, k_tv unchanged from R9.
// ---------------------------------------------------------------------------

typedef __attribute__((ext_vector_type(8))) short short8;   // 8 bf16 (4 VGPRs)
typedef __attribute__((ext_vector_type(4))) float floatx4;  // MFMA C/D frag

#define AS1C(p) ((const __attribute__((address_space(1))) void*)(p))
#define AS3(p)  ((__attribute__((address_space(3))) void*)(p))
#define GL16(src, dst) __builtin_amdgcn_global_load_lds(AS1C(src), AS3(dst), 16, 0, 0)
#define BARRIER() do { asm volatile("" ::: "memory"); __builtin_amdgcn_s_barrier(); asm volatile("" ::: "memory"); } while (0)

__device__ __forceinline__ unsigned short f2bf(float f) {
  unsigned int u = __builtin_bit_cast(unsigned int, f);
  u = (u + 0x7fffu + ((u >> 16) & 1u)) >> 16;   // RNE
  return (unsigned short)u;
}
__device__ __forceinline__ unsigned short f2bf_trunc(float f) {
  return (unsigned short)(__builtin_bit_cast(unsigned int, f) >> 16);
}

// ---------------------------------------------------------------------------
// Fused prep: [0,8192) cvt x->bf16; [8192,11264) tw W_attn; [11264,12288) tw
// W_proj.
// ---------------------------------------------------------------------------
__global__ __launch_bounds__(256)
void k_prep(const float* __restrict__ x, unsigned short* __restrict__ xb,
            const float* __restrict__ Wa, unsigned short* __restrict__ WaT,
            const float* __restrict__ Wp, unsigned short* __restrict__ WpT) {
  __shared__ float t[32][33];
  int bid = blockIdx.x;
  int tid = threadIdx.x;
  if (bid < 8192) {
    int i = bid * 256 + tid;           // n4 = 2097152 = 8192*256 exactly
    float4 v = ((const float4*)x)[i];
    ushort4 o;
    o.x = f2bf(v.x); o.y = f2bf(v.y); o.z = f2bf(v.z); o.w = f2bf(v.w);
    ((ushort4*)xb)[i] = o;
    return;
  }
  const float* in; unsigned short* out; int K = 1024, N, n0, k0;
  if (bid < 11264) {                   // W_attn: 96x32 tiles of [1024][3072]
    int b2 = bid - 8192;
    in = Wa; out = WaT; N = 3072;
    n0 = (b2 % 96) * 32; k0 = (b2 / 96) * 32;
  } else {                             // W_proj: 32x32 tiles of [1024][1024]
    int b2 = bid - 11264;
    in = Wp; out = WpT; N = 1024;
    n0 = (b2 % 32) * 32; k0 = (b2 / 32) * 32;
  }
  int tx = tid & 31, ty = tid >> 5;
#pragma unroll
  for (int i = 0; i < 4; i++)
    t[ty + 8 * i][tx] = in[(size_t)(k0 + ty + 8 * i) * N + n0 + tx];
  __syncthreads();
#pragma unroll
  for (int i = 0; i < 4; i++)
    out[(size_t)(n0 + ty + 8 * i) * K + k0 + tx] = f2bf(t[tx][ty + 8 * i]);
}

// ---- transpose V slice of qkv (bf16) -> VT[bh][d][t], 64-wide tiles ----
__global__ __launch_bounds__(256)
void k_tv(const unsigned short* __restrict__ qkv, unsigned short* __restrict__ vt) {
  __shared__ unsigned short t[64][65];
  int t0 = blockIdx.x * 64;         // time tile
  int bh = blockIdx.y;              // 0..63
  int b = bh >> 4, h = bh & 15;
  int tx = threadIdx.x & 63, ty = threadIdx.x >> 6;   // 64 x 4
#pragma unroll
  for (int i = 0; i < 16; i++)
    t[ty + 4 * i][tx] = qkv[(size_t)(b * 2048 + t0 + ty + 4 * i) * 3072 + 2048 + h * 64 + tx];
  __syncthreads();
#pragma unroll
  for (int i = 0; i < 16; i++)
    vt[(size_t)(bh * 64 + ty + 4 * i) * 2048 + t0 + tx] = t[tx][ty + 4 * i];
}

// ---------------------------------------------------------------------------
// 256x(NF*64)-tile bf16 GEMM, C = A[M,K] @ Bt[N,K]^T + bias.
// A+B double-buffered; one barrier + one vmcnt per K-tile (R8 schedule).
// ---------------------------------------------------------------------------
template <int OUT_F32, int NF>
__global__ __launch_bounds__(512, 2)
void k_gemm8(const unsigned short* __restrict__ A,
             const unsigned short* __restrict__ Bt,
             const float* __restrict__ bias,
             void* __restrict__ Cout, int M, int N, int K) {
  __shared__ unsigned short lA[2][256 * 64];        // 64 KiB
  __shared__ unsigned short lB[2][NF * 64 * 64];    // 48 (NF=3) / 32 (NF=2) KiB
  int tid = threadIdx.x;
  int lane = tid & 63, wv = tid >> 6;               // 8 waves
  int lc = lane & 15, quad = lane >> 4;
  int sw = lc & 7;

  // T1: XCD-aware block swizzle (nwg % 8 == 0 for both launches)
  unsigned nbx = gridDim.x;
  unsigned nwg = nbx * gridDim.y;
  unsigned flat = blockIdx.y * nbx + blockIdx.x;
  unsigned cpx = nwg >> 3;
  unsigned tile = (flat & 7u) * cpx + (flat >> 3);
  int n0 = (int)(tile % nbx) * (NF * 64);
  int m0 = (int)(tile / nbx) * 256;

  int wm = (wv >> 2) * 128;         // 0,128
  int wn = (wv & 3) * (NF * 16);    // 4 N-waves

  floatx4 acc[8][NF];
#pragma unroll
  for (int i = 0; i < 8; i++)
#pragma unroll
    for (int j = 0; j < NF; j++) acc[i][j] = (floatx4){0.f, 0.f, 0.f, 0.f};

  // staging geometry: one gload issue = 512 thr x 16B = 8 KiB = 64 rows
  int srow = tid >> 3;                          // 0..63
  int scol = ((tid & 7) ^ (srow & 7)) * 8;      // inverse-swizzled source chunk
  const unsigned short* gA = A + (size_t)(m0 + srow) * K + scol;
  const unsigned short* gB = Bt + (size_t)(n0 + srow) * K + scol;

  int NT = K >> 6;

  // prologue: stage K-tile 0 into parity 0; wait; barrier.
#pragma unroll
  for (int i = 0; i < 4; i++)  GL16(gA + (size_t)(i * 64) * K, &lA[0][i * 4096 + wv * 512]);
#pragma unroll
  for (int i = 0; i < NF; i++) GL16(gB + (size_t)(i * 64) * K, &lB[0][i * 4096 + wv * 512]);
  asm volatile("s_waitcnt vmcnt(0)" ::: "memory");
  __builtin_amdgcn_s_barrier();
  asm volatile("" ::: "memory");

  for (int t = 0; t < NT; ++t) {
    const unsigned short* bufA = lA[t & 1];
    const unsigned short* bufB = lB[t & 1];
    bool st = (t + 1) < NT;

    // issue next tile's staging FIRST (full-tile latency cover).
    if (st) {
      unsigned short* nA = lA[(t + 1) & 1];
      unsigned short* nB = lB[(t + 1) & 1];
      int k1 = (t + 1) << 6;
#pragma unroll
      for (int i = 0; i < 4; i++)
        GL16(gA + (size_t)(i * 64) * K + k1, nA + i * 4096 + wv * 512);
#pragma unroll
      for (int i = 0; i < NF; i++)
        GL16(gB + (size_t)(i * 64) * K + k1, nB + i * 4096 + wv * 512);
    }

    // ---- compute tile t: one barrier-free region ----
    short8 af[4][2], bf[NF][2];
#pragma unroll
    for (int n = 0; n < NF; n++)
#pragma unroll
      for (int ks = 0; ks < 2; ks++)
        bf[n][ks] = *(const short8*)(bufB + (wn + n * 16 + lc) * 64 + (((ks * 4 + quad) ^ sw) * 8));
#pragma unroll
    for (int m = 0; m < 4; m++)
#pragma unroll
      for (int ks = 0; ks < 2; ks++)
        af[m][ks] = *(const short8*)(bufA + (wm + m * 16 + lc) * 64 + (((ks * 4 + quad) ^ sw) * 8));
    __builtin_amdgcn_s_setprio(1);
#pragma unroll
    for (int m = 0; m < 4; m++)
#pragma unroll
      for (int n = 0; n < NF; n++)
#pragma unroll
        for (int ks = 0; ks < 2; ks++)
          acc[m][n] = __builtin_amdgcn_mfma_f32_16x16x32_bf16(af[m][ks], bf[n][ks], acc[m][n], 0, 0, 0);
    __builtin_amdgcn_s_setprio(0);
#pragma unroll
    for (int m = 0; m < 4; m++)
#pragma unroll
      for (int ks = 0; ks < 2; ks++)
        af[m][ks] = *(const short8*)(bufA + (wm + (m + 4) * 16 + lc) * 64 + (((ks * 4 + quad) ^ sw) * 8));
    __builtin_amdgcn_s_setprio(1);
#pragma unroll
    for (int m = 0; m < 4; m++)
#pragma unroll
      for (int n = 0; n < NF; n++)
#pragma unroll
        for (int ks = 0; ks < 2; ks++)
          acc[m + 4][n] = __builtin_amdgcn_mfma_f32_16x16x32_bf16(af[m][ks], bf[n][ks], acc[m + 4][n], 0, 0, 0);
    __builtin_amdgcn_s_setprio(0);

    // ---- tile boundary: t+1 landed (issued a full tile ago) + barrier ----
    if (st) {
      asm volatile("s_waitcnt vmcnt(0)" ::: "memory");
      BARRIER();
    }
  }

  // ---- epilogue ----
  float bv[NF];
#pragma unroll
  for (int j = 0; j < NF; j++) bv[j] = bias[n0 + wn + j * 16 + lc];
#pragma unroll
  for (int i = 0; i < 8; i++) {
#pragma unroll
    for (int j = 0; j < NF; j++) {
#pragma unroll
      for (int r = 0; r < 4; r++) {
        size_t idx = (size_t)(m0 + wm + i * 16 + quad * 4 + r) * N + (n0 + wn + j * 16 + lc);
        float v = acc[i][j][r] + bv[j];
        if (OUT_F32) ((float*)Cout)[idx] = v;
        else         ((unsigned short*)Cout)[idx] = f2bf(v);
      }
    }
  }
}

// ---- flash attention: paired q-tiles, XCD-grouped, split-wait schedule ----
#define LP_STRIDE 68   // pad: pf b128 reads land 2-way/bank (free)
__global__ __launch_bounds__(256, 4)
void k_flash(const unsigned short* __restrict__ qkv,
             const unsigned short* __restrict__ vt,
             unsigned short* __restrict__ y) {
  __shared__ unsigned short lK[64 * 64];
  __shared__ unsigned short lVT[64 * 64];
  __shared__ unsigned short lP[4][2][16 * LP_STRIDE];
  int tid = threadIdx.x, lane = tid & 63, wv = tid >> 6;
  int lc = lane & 15, quad = lane >> 4;
  int sw = lc & 7;

  // XCD grouping: each XCD owns 8 bh values with ALL 16 q-pair blocks.
  int raw = blockIdx.y * 16 + blockIdx.x;      // 0..1023
  int bh  = (raw & 7) * 8 + ((raw >> 3) & 7);  // 0..63
  int j   = raw >> 6;                          // 0..15
  int b = bh >> 4, h = bh & 15;
  int qtA = j, qtB = 31 - j;
  int qrA = qtA * 64 + wv * 16;
  int qrB = qtB * 64 + wv * 16;

  short8 qfA[2], qfB[2];
  {
    const unsigned short* qp = qkv + (size_t)(b * 2048 + qrA + lc) * 3072 + h * 64 + quad * 8;
    qfA[0] = *(const short8*)qp;
    qfA[1] = *(const short8*)(qp + 32);
  }
  {
    const unsigned short* qp = qkv + (size_t)(b * 2048 + qrB + lc) * 3072 + h * 64 + quad * 8;
    qfB[0] = *(const short8*)qp;
    qfB[1] = *(const short8*)(qp + 32);
  }

  float rsA[4] = {0.f, 0.f, 0.f, 0.f}, rsB[4] = {0.f, 0.f, 0.f, 0.f};
  floatx4 oA[4], oB[4];
#pragma unroll
  for (int dt = 0; dt < 4; dt++) {
    oA[dt] = (floatx4){0.f, 0.f, 0.f, 0.f};
    oB[dt] = (floatx4){0.f, 0.f, 0.f, 0.f};
  }

  int srow = tid >> 3;
  int scol = ((tid & 7) ^ (srow & 7)) * 8;    // swizzled gather column
  const unsigned short* gK = qkv + (size_t)(b * 2048 + srow) * 3072 + 1024 + h * 64 + scol;
  const unsigned short* gV = vt + (size_t)(bh * 64 + srow) * 2048 + scol;

  const float SC2 = 0.18033688011f;   // (1/sqrt(64)) * log2(e)
  int nt = qtB + 1;

  // prologue: issue K(0) only (V(0) issued at iter top).
#pragma unroll
  for (int c = 0; c < 2; c++)
    GL16(gK + (size_t)(32 * c) * 3072, lK + (32 * c + 8 * wv) * 64);

  for (int kv = 0; kv < nt; kv++) {
    int kv0 = kv * 64;

    // (1) issue V(kv); (2) wait K(kv) only: the 2 newest ops are V(kv).
#pragma unroll
    for (int c = 0; c < 2; c++)
      GL16(gV + (size_t)(32 * c) * 2048 + kv0, lVT + (32 * c + 8 * wv) * 64);
    asm volatile("s_waitcnt vmcnt(2)" ::: "memory");
    BARRIER();   // all waves have K(kv)

    bool withA = (kv <= qtA);

    // ---- (3) S = Q K^T for both q-tiles, sharing K fragments ----
    floatx4 sB[4], sA[4];
    __builtin_amdgcn_s_setprio(1);
#pragma unroll
    for (int n = 0; n < 4; n++) {
      short8 kf0 = *(const short8*)(lK + (n * 16 + lc) * 64 + ((quad ^ sw) * 8));
      short8 kf1 = *(const short8*)(lK + (n * 16 + lc) * 64 + (((4 + quad) ^ sw) * 8));
      floatx4 t = (floatx4){0.f, 0.f, 0.f, 0.f};
      t = __builtin_amdgcn_mfma_f32_16x16x32_bf16(qfB[0], kf0, t, 0, 0, 0);
      t = __builtin_amdgcn_mfma_f32_16x16x32_bf16(qfB[1], kf1, t, 0, 0, 0);
      sB[n] = t;
      if (withA) {
        floatx4 u = (floatx4){0.f, 0.f, 0.f, 0.f};
        u = __builtin_amdgcn_mfma_f32_16x16x32_bf16(qfA[0], kf0, u, 0, 0, 0);
        u = __builtin_amdgcn_mfma_f32_16x16x32_bf16(qfA[1], kf1, u, 0, 0, 0);
        sA[n] = u;
      }
    }
    __builtin_amdgcn_s_setprio(0);

    // ---- softmax numerators (no max subtraction), P -> LDS (trunc pack) ----
    {
      bool diag = (kv == qtB);
#pragma unroll
      for (int n = 0; n < 4; n++)
#pragma unroll
        for (int r = 0; r < 4; r++) {
          float arg = sB[n][r] * SC2;
          if (diag && (kv0 + n * 16 + lc > qrB + quad * 4 + r)) arg = -__builtin_inff();
          float p = __builtin_amdgcn_exp2f(arg);
          rsB[r] += p;
          lP[wv][0][(quad * 4 + r) * LP_STRIDE + n * 16 + lc] = f2bf_trunc(p);
        }
    }
    if (withA) {
      bool diag = (kv == qtA);
#pragma unroll
      for (int n = 0; n < 4; n++)
#pragma unroll
        for (int r = 0; r < 4; r++) {
          float arg = sA[n][r] * SC2;
          if (diag && (kv0 + n * 16 + lc > qrA + quad * 4 + r)) arg = -__builtin_inff();
          float p = __builtin_amdgcn_exp2f(arg);
          rsA[r] += p;
          lP[wv][1][(quad * 4 + r) * LP_STRIDE + n * 16 + lc] = f2bf_trunc(p);
        }
    }

    // (4) V(kv) landed (issued at iter top; latency hidden under QK^T+softmax)
    asm volatile("s_waitcnt vmcnt(0)" ::: "memory");
    BARRIER();

    // (5) issue K(kv+1): legal single-buffered -- every wave's lK reads
    // retired (consumed by MFMAs) before its mid-barrier above.
    if (kv + 1 < nt) {
      int kn0 = kv0 + 64;
#pragma unroll
      for (int c = 0; c < 2; c++)
        GL16(gK + (size_t)(kn0 + 32 * c) * 3072, lK + (32 * c + 8 * wv) * 64);
    }

    // ---- (6) O += P @ V, sharing V fragments ----
    __builtin_amdgcn_s_setprio(1);
#pragma unroll
    for (int s2 = 0; s2 < 2; s2++) {
      short8 pfB = *(const short8*)(&lP[wv][0][0] + lc * LP_STRIDE + s2 * 32 + quad * 8);
      short8 pfA;
      if (withA) pfA = *(const short8*)(&lP[wv][1][0] + lc * LP_STRIDE + s2 * 32 + quad * 8);
#pragma unroll
      for (int dt = 0; dt < 4; dt++) {
        short8 vf = *(const short8*)(lVT + (dt * 16 + lc) * 64 + (((s2 * 4 + quad) ^ sw) * 8));
        oB[dt] = __builtin_amdgcn_mfma_f32_16x16x32_bf16(pfB, vf, oB[dt], 0, 0, 0);
        if (withA) oA[dt] = __builtin_amdgcn_mfma_f32_16x16x32_bf16(pfA, vf, oA[dt], 0, 0, 0);
      }
    }
    __builtin_amdgcn_s_setprio(0);
    BARRIER();   // (7) protect lVT before next iter's V writes
  }

  // ---- epilogue: one row-sum butterfly, normalize, store both tiles ----
#pragma unroll
  for (int off = 1; off < 16; off <<= 1)
#pragma unroll
    for (int r = 0; r < 4; r++) {
      rsA[r] += __shfl_xor(rsA[r], off);
      rsB[r] += __shfl_xor(rsB[r], off);
    }
#pragma unroll
  for (int r = 0; r < 4; r++) {
    float invA = 1.0f / rsA[r];
    float invB = 1.0f / rsB[r];
#pragma unroll
    for (int dt = 0; dt < 4; dt++) {
      size_t ia = (size_t)(b * 2048 + qrA + quad * 4 + r) * 1024 + h * 64 + dt * 16 + lc;
      size_t ib = (size_t)(b * 2048 + qrB + quad * 4 + r) * 1024 + h * 64 + dt * 16 + lc;
      y[ia] = f2bf(oA[dt][r] * invA);
      y[ib] = f2bf(oB[dt][r] * invB);
    }
  }
}

extern "C" void kernel_launch(void* const* d_in, const int* in_sizes, int n_in,
                              void* d_out, int out_size, void* d_ws, size_t ws_size,
                              hipStream_t stream) {
  const float* x      = (const float*)d_in[0];
  const float* W_attn = (const float*)d_in[1];
  const float* b_attn = (const float*)d_in[2];
  const float* W_proj = (const float*)d_in[3];
  const float* b_proj = (const float*)d_in[4];

  char* ws = (char*)d_ws;
  unsigned short* xb     = (unsigned short*)ws;                    // 16.8 MB (reused as y)
  unsigned short* wattnT = (unsigned short*)(ws + 16777216);       // 6.3 MB
  unsigned short* wprojT = (unsigned short*)(ws + 23068672);       // 2.1 MB
  unsigned short* qkv    = (unsigned short*)(ws + 25165824);       // 50.3 MB
  unsigned short* vt     = (unsigned short*)(ws + 75497472);       // 16.8 MB -> total 92.3 MB
  unsigned short* y      = xb;   // xb dead after QKV GEMM

  // fused prep: cvt (8192 blocks) + tw W_attn (3072) + tw W_proj (1024)
  k_prep<<<12288, 256, 0, stream>>>(x, xb, W_attn, wattnT, W_proj, wprojT);
  // QKV GEMM: 256x192 tiles, grid 16x32 = 512 blocks = 2 exact rounds
  k_gemm8<0, 3><<<dim3(16, 32), 512, 0, stream>>>(xb, wattnT, b_attn, qkv, 8192, 3072, 1024);
  // V transpose: 64-wide tiles, fully coalesced
  k_tv<<<dim3(32, 64), 256, 0, stream>>>(qkv, vt);
  k_flash<<<dim3(16, 64), 256, 0, stream>>>(qkv, vt, y);
  // proj GEMM: 256x128 tiles, grid 8x32 = 256 blocks = 1 exact round
  k_gemm8<1, 2><<<dim3(8, 32), 512, 0, stream>>>(y, wprojT, b_proj, d_out, 8192, 1024, 1024);
}